// Round 1
// baseline (82.870 us; speedup 1.0000x reference)
//
#include <hip/hip_runtime.h>
#include <math.h>

// EEGSDE: OU Euler-Maruyama step with antithetic variates + ERP jump injection.
// paths[n,b,c,t] = x[b,c,t]*(1 - theta*dt) + s*sqrt(dt)*sigma*eps[n%32,b,c,t]
//                  + mask[n,b,c]*0.2*mag[n,b,c]*exp(-0.5*((t - jt[n,b,c])/10)^2)
// where s = +1 for n<32, -1 for n>=32.

#define DT_F 0.01f
#define THETA0 2.0f
#define SIGMA0 0.5f
#define JUMP_RATE 0.1f
#define JUMP_SCALE 0.2f
#define ERP_INV_W 0.1f   // 1/10

constexpr int B_ = 16;
constexpr int C_ = 64;
constexpr int T_ = 1000;
constexpr int NH_ = 32;          // N_paths / 2
constexpr int BC_ = B_ * C_;     // 1024
constexpr int CHUNKS_ = T_ / 4;  // 250 float4 chunks per row
constexpr int NH_PER_BLK = 8;    // gridDim.y = NH_/NH_PER_BLK = 4

__global__ __launch_bounds__(256) void eegsde_paths_kernel(
    const float* __restrict__ x,            // [B,C,T]
    const float* __restrict__ theta_scale,  // [1]
    const float* __restrict__ sigma_scale,  // [1]
    const float* __restrict__ eps,          // [NH,B,C,T]
    const float* __restrict__ jump_rand,    // [N,B,C]
    const float* __restrict__ jump_mag,     // [N,B,C]
    const int*   __restrict__ jump_times,   // [N,B,C]
    float* __restrict__ out)                // [N,B,C,T]
{
    const int bc = blockIdx.x;       // 0..1023  (b*C + c)
    const int tc = threadIdx.x;      // 0..255
    if (tc >= CHUNKS_) return;
    const int t0 = tc * 4;

    const float theta = THETA0 * fabsf(theta_scale[0]);
    const float sigma = SIGMA0 * fabsf(sigma_scale[0]);
    const float a  = 1.0f - theta * DT_F;         // drift: x + theta*(0-x)*dt
    const float sd = sqrtf(DT_F) * sigma;         // dW scale

    // x is reused by all 32 nh iterations: load once into registers.
    const float4 x4 = *reinterpret_cast<const float4*>(&x[bc * T_ + t0]);
    const float bx0 = a * x4.x;
    const float bx1 = a * x4.y;
    const float bx2 = a * x4.z;
    const float bx3 = a * x4.w;

    const float tf0 = (float)t0;
    const float tf1 = tf0 + 1.0f;
    const float tf2 = tf0 + 2.0f;
    const float tf3 = tf0 + 3.0f;

    const int nh_begin = blockIdx.y * NH_PER_BLK;
    const int nh_end   = nh_begin + NH_PER_BLK;

    #pragma unroll 2
    for (int nh = nh_begin; nh < nh_end; ++nh) {
        const int row = nh * BC_ + bc;            // row index into eps / out[nh]
        const int jid0 = row;                     // jump params for path nh
        const int jid1 = (nh + NH_) * BC_ + bc;   // jump params for path nh+32

        // Per-row (wave-uniform) jump scalars — cache-broadcast loads.
        const float amp0 = (jump_rand[jid0] < JUMP_RATE) ? (JUMP_SCALE * jump_mag[jid0]) : 0.0f;
        const float amp1 = (jump_rand[jid1] < JUMP_RATE) ? (JUMP_SCALE * jump_mag[jid1]) : 0.0f;
        const float jt0 = (float)jump_times[jid0];
        const float jt1 = (float)jump_times[jid1];

        const float4 e4 = *reinterpret_cast<const float4*>(&eps[(size_t)row * T_ + t0]);

        const float dw0 = sd * e4.x;
        const float dw1 = sd * e4.y;
        const float dw2 = sd * e4.z;
        const float dw3 = sd * e4.w;

        // ERP bumps (8 fast-exps per chunk; VALU is ~12% of HBM time)
        const float d00 = (tf0 - jt0) * ERP_INV_W;
        const float d01 = (tf1 - jt0) * ERP_INV_W;
        const float d02 = (tf2 - jt0) * ERP_INV_W;
        const float d03 = (tf3 - jt0) * ERP_INV_W;
        const float d10 = (tf0 - jt1) * ERP_INV_W;
        const float d11 = (tf1 - jt1) * ERP_INV_W;
        const float d12 = (tf2 - jt1) * ERP_INV_W;
        const float d13 = (tf3 - jt1) * ERP_INV_W;

        const float j00 = amp0 * __expf(-0.5f * d00 * d00);
        const float j01 = amp0 * __expf(-0.5f * d01 * d01);
        const float j02 = amp0 * __expf(-0.5f * d02 * d02);
        const float j03 = amp0 * __expf(-0.5f * d03 * d03);
        const float j10 = amp1 * __expf(-0.5f * d10 * d10);
        const float j11 = amp1 * __expf(-0.5f * d11 * d11);
        const float j12 = amp1 * __expf(-0.5f * d12 * d12);
        const float j13 = amp1 * __expf(-0.5f * d13 * d13);

        float4 o0, o1;
        o0.x = bx0 + dw0 + j00;
        o0.y = bx1 + dw1 + j01;
        o0.z = bx2 + dw2 + j02;
        o0.w = bx3 + dw3 + j03;
        o1.x = bx0 - dw0 + j10;
        o1.y = bx1 - dw1 + j11;
        o1.z = bx2 - dw2 + j12;
        o1.w = bx3 - dw3 + j13;

        *reinterpret_cast<float4*>(&out[(size_t)row * T_ + t0]) = o0;
        *reinterpret_cast<float4*>(&out[(size_t)((nh + NH_) * BC_ + bc) * T_ + t0]) = o1;
    }
}

extern "C" void kernel_launch(void* const* d_in, const int* in_sizes, int n_in,
                              void* d_out, int out_size, void* d_ws, size_t ws_size,
                              hipStream_t stream) {
    const float* x           = (const float*)d_in[0];
    const float* theta_scale = (const float*)d_in[1];
    const float* sigma_scale = (const float*)d_in[2];
    const float* eps         = (const float*)d_in[3];
    const float* jump_rand   = (const float*)d_in[4];
    const float* jump_mag    = (const float*)d_in[5];
    const int*   jump_times  = (const int*)d_in[6];
    float* out = (float*)d_out;

    dim3 grid(BC_, NH_ / NH_PER_BLK, 1);  // (1024, 4)
    dim3 block(256, 1, 1);
    eegsde_paths_kernel<<<grid, block, 0, stream>>>(
        x, theta_scale, sigma_scale, eps, jump_rand, jump_mag, jump_times, out);
}